// Round 4
// baseline (1466.648 us; speedup 1.0000x reference)
//
#include <hip/hip_runtime.h>
#include <stdint.h>

// FusedGPTQMLP on MI355X (gfx950).
// Round 10: revert to the best measured GEMM structure (R7: 256x256 tile,
// 8 waves, 4 phases x 16 MFMA, 2 barriers/phase) and FUSE the GPTQ dequant
// into the GEMM's B-staging: B is staged as raw int32 qweight (L3-resident,
// 4x fewer bytes) + scale/zero, expanded in-register (cvt_f32_ubyte ->
// fma(q,s,-(z+1)s) -> v_cvt_pk_bf16_f32) and ds_written into the packet
// layout. Removes the dequant kernels and the 90MB wb HBM round-trip.
// ws: xb [M,HIDDEN] bf16 | gi [MC,INTER] bf16.

#define HIDDEN 4096
#define INTER  11008
#define BM 256
#define BN 256
#define BK 64

typedef __bf16 bf16x8 __attribute__((ext_vector_type(8)));
typedef float f32x4 __attribute__((ext_vector_type(4)));

__device__ __forceinline__ ushort f2bf_rne(float f) {
  uint32_t u = __float_as_uint(f);
  u += 0x7FFFu + ((u >> 16) & 1u);
  return (ushort)(u >> 16);
}

__device__ __forceinline__ float bf2f(ushort h) {
  return __uint_as_float(((uint32_t)h) << 16);
}

// fp32 -> bf16 bulk convert, 4 elements/thread.
__global__ void f32_to_bf16_kernel(const float* __restrict__ src,
                                   ushort* __restrict__ dst, int n4) {
  const int i = blockIdx.x * 256 + threadIdx.x;
  if (i < n4) {
    const float4 v = ((const float4*)src)[i];
    ushort4 o;
    o.x = f2bf_rne(v.x); o.y = f2bf_rne(v.y);
    o.z = f2bf_rne(v.z); o.w = f2bf_rne(v.w);
    ((ushort4*)dst)[i] = o;
  }
}

#define GL_LDS(gp, lp)                                                        \
  __builtin_amdgcn_global_load_lds(                                           \
      (const __attribute__((address_space(1))) uint32_t*)(gp),                \
      (__attribute__((address_space(3))) uint32_t*)(lp), 16, 0, 0)
#define BAR()  do { __builtin_amdgcn_s_barrier(); asm volatile("" ::: "memory"); } while (0)
#define WVM4() asm volatile("s_waitcnt vmcnt(4)" ::: "memory")
#define WVM0() asm volatile("s_waitcnt vmcnt(0)" ::: "memory")
#define WLG0() asm volatile("s_waitcnt lgkmcnt(0)" ::: "memory")

// Expand one GPTQ int32 packet (8 nibbles along K) -> 8 bf16 = uint4.
// w_j = q_j * s - (z+1)*s, computed as fma(q_j, s, nz1s); bf16 RNE pack.
__device__ __forceinline__ uint4 expand_packet(uint32_t v, float s, float nz1s) {
  const uint32_t lo = v & 0x0F0F0F0Fu;         // nibbles 0,2,4,6 as bytes
  const uint32_t hi = (v >> 4) & 0x0F0F0F0Fu;  // nibbles 1,3,5,7 as bytes
  uint4 o;
  float a0, a1;
  a0 = fmaf((float)(lo & 0xFFu), s, nz1s);
  a1 = fmaf((float)(hi & 0xFFu), s, nz1s);
  asm("v_cvt_pk_bf16_f32 %0, %1, %2" : "=v"(o.x) : "v"(a0), "v"(a1));
  a0 = fmaf((float)((lo >> 8) & 0xFFu), s, nz1s);
  a1 = fmaf((float)((hi >> 8) & 0xFFu), s, nz1s);
  asm("v_cvt_pk_bf16_f32 %0, %1, %2" : "=v"(o.y) : "v"(a0), "v"(a1));
  a0 = fmaf((float)((lo >> 16) & 0xFFu), s, nz1s);
  a1 = fmaf((float)((hi >> 16) & 0xFFu), s, nz1s);
  asm("v_cvt_pk_bf16_f32 %0, %1, %2" : "=v"(o.z) : "v"(a0), "v"(a1));
  a0 = fmaf((float)(lo >> 24), s, nz1s);
  a1 = fmaf((float)(hi >> 24), s, nz1s);
  asm("v_cvt_pk_bf16_f32 %0, %1, %2" : "=v"(o.w) : "v"(a0), "v"(a1));
  return o;
}

// C[m, n] = A[m, :] @ W[:, n], W dequantized on the fly from GPTQ 4-bit.
// A: bf16 [rows, lda] (pre-offset). qw: [K/8, Nfull] int32 (8 k-nibbles).
// sc: [K/128, Nfull] fp32. zr: [K/128, Nfull/8] int32 (8 n-nibbles).
// MODE 0: C bf16 = result. MODE 1: C bf16 = silu(C_old) * result (SwiGLU).
// MODE 2: C fp32 = result.
// Structure: R7 (best measured): 256x256 tile, BK=64, 8 waves (2M x 4N),
// wave tile 128x64, 4 phases x 16 MFMA, 2 barriers/phase. A staged via
// global_load_lds with XOR-swizzled source; B staged via registers:
// PH1 issues next-step qweight/scale/zero loads, PH4 expands + ds_writes
// into the other buffer. vmcnt(4) at PH3-end (B ints landed), vmcnt(0) at
// step boundary (A stages landed, issued >=2 phases earlier).
template <int MODE>
__launch_bounds__(512, 2)
__global__ void gemm_fused_kernel(const ushort* __restrict__ A,
                                  const int32_t* __restrict__ qw,
                                  const float* __restrict__ sc,
                                  const int32_t* __restrict__ zr,
                                  void* __restrict__ Cv,
                                  int K, int Nfull, int lda, int ldc) {
  __shared__ ushort sAs[2][BM * BK];            // 2 x 32 KB
  __shared__ ushort sBs[2][(BK / 8) * BN * 8];  // 2 x 32 KB packet layout

  const int tid = threadIdx.x;
  const int w = tid >> 6;
  const int lane = tid & 63;
  const int l16 = lane & 15;
  const int quad = lane >> 4;
  const int wm16 = (w >> 2) * 16;   // 2 waves along M
  const int wn = (w & 3) * 64;      // 4 waves along N
  const int swz = l16 & 7;          // A-tile XOR swizzle key (row & 7)

  // Bijective XCD-aware block swizzle (m204 form).
  const int gx = gridDim.x;
  const int nwg = gx * (int)gridDim.y;
  const int orig = blockIdx.y * gx + blockIdx.x;
  const int q8 = nwg >> 3, r8 = nwg & 7;
  const int xcd = orig & 7, sidx = orig >> 3;
  const int wg = (xcd < r8 ? xcd * (q8 + 1) : r8 * (q8 + 1) + (xcd - r8) * q8) + sidx;
  const int m0 = (wg / gx) * BM;
  const int bn0 = (wg % gx) * BN;

  // A staging lane geometry (source pre-swizzled; LDS dest linear).
  const int arow = tid >> 3;                      // 0..63 within 64-row slab
  const int apk8 = ((tid & 7) ^ (arow & 7)) * 8;  // swizzled source packet
  const ushort* aSrc = A + (size_t)(m0 + arow) * lda + apk8;

  // B dequant lane geometry: thread owns column bcol, packet-rows prg+2r.
  const int bcol = tid & 255;
  const int prg = tid >> 8;                       // 0..1
  const int32_t* qcol = qw + bn0 + bcol;
  const float* scol = sc + bn0 + bcol;
  const int32_t* zcol = zr + ((bn0 + bcol) >> 3);
  const int zsh = (bcol & 7) * 4;

  f32x4 acc[8][4];
#pragma unroll
  for (int a = 0; a < 8; a++)
#pragma unroll
    for (int j = 0; j < 4; j++) acc[a][j] = (f32x4){0.f, 0.f, 0.f, 0.f};

  const int NT = K / BK;

#define STAGE_A(r, buf, kt) \
  GL_LDS(aSrc + (size_t)(r) * 64 * lda + (kt), (buf) + (r) * 4096 + w * 512)

  // Load next-step B ints + scale + zero (6 VMEM; group g = step>>1).
  uint32_t b4[4]; float sNx; uint32_t zNx;
#define LOADB(s)                                                   \
  do {                                                             \
    const size_t rb = (size_t)(s) * 8 + prg;                       \
    b4[0] = (uint32_t)qcol[(rb + 0) * (size_t)Nfull];              \
    b4[1] = (uint32_t)qcol[(rb + 2) * (size_t)Nfull];              \
    b4[2] = (uint32_t)qcol[(rb + 4) * (size_t)Nfull];              \
    b4[3] = (uint32_t)qcol[(rb + 6) * (size_t)Nfull];              \
    sNx = scol[(size_t)((s) >> 1) * Nfull];                        \
    zNx = (uint32_t)zcol[(size_t)((s) >> 1) * (Nfull >> 3)];       \
  } while (0)

  // Expand held ints -> bf16 packets -> ds_write into buf (packet layout).
#define EXPB(buf)                                                        \
  do {                                                                   \
    const int z1 = (int)((zNx >> zsh) & 15u) + 1;                        \
    const float nz = -((float)z1 * sNx);                                 \
    _Pragma("unroll") for (int r = 0; r < 4; r++) {                      \
      const uint4 pk = expand_packet(b4[r], sNx, nz);                    \
      *(uint4*)((buf) + ((size_t)(prg + 2 * r) * 256 + bcol) * 8) = pk;  \
    }                                                                    \
  } while (0)

#define MM16(base)                                                       \
  do {                                                                   \
    __builtin_amdgcn_s_setprio(1);                                       \
    _Pragma("unroll") for (int i = 0; i < 4; i++)                        \
    _Pragma("unroll") for (int j = 0; j < 4; j++)                        \
      acc[(base) + i][j] = __builtin_amdgcn_mfma_f32_16x16x32_bf16(      \
          af[i], bf[j], acc[(base) + i][j], 0, 0, 0);                    \
    __builtin_amdgcn_s_setprio(0);                                       \
  } while (0)

  // Prologue: B ints(step0) + A stages(step0); expand B0; drain; barrier.
  LOADB(0);
  STAGE_A(0, sAs[0], (size_t)0); STAGE_A(1, sAs[0], (size_t)0);
  STAGE_A(2, sAs[0], (size_t)0); STAGE_A(3, sAs[0], (size_t)0);
  WVM4();            // b4/s/z landed (oldest 6 of 10)
  EXPB(sBs[0]);
  WVM0(); WLG0();    // A landed; ds_writes drained
  BAR();

  for (int t = 0; t < NT; ++t) {
    const ushort* sAc = sAs[t & 1];
    const ushort* sBc = sBs[t & 1];
    ushort* sAn = sAs[(t & 1) ^ 1];
    ushort* sBn = sBs[(t & 1) ^ 1];
    const int tn = (t + 1 < NT) ? t + 1 : t;  // clamp: re-stage last step
    const size_t ktn = (size_t)tn * BK;

    bf16x8 af[4], bf[4];
    const ushort* pA0 = sAc + (size_t)(wm16 + l16) * 64 + ((quad ^ swz) * 8);
    const ushort* pA1 = sAc + (size_t)(wm16 + l16) * 64 + (((4 ^ quad) ^ swz) * 8);

    // ---- PH1: rows0-127 x kk0 ; issue next B ints/scale/zero ----
#pragma unroll
    for (int i = 0; i < 4; i++) af[i] = *(const bf16x8*)(pA0 + i * 2048);
#pragma unroll
    for (int j = 0; j < 4; j++)
      bf[j] = *(const bf16x8*)(sBc + ((size_t)(quad * 256) + wn + j * 16 + l16) * 8);
    LOADB(tn);
    BAR(); WLG0();
    MM16(0);
    BAR();

    // ---- PH2: rows128-255 x kk0 (bf reused) ; stage next A (lo) ----
#pragma unroll
    for (int i = 0; i < 4; i++) af[i] = *(const bf16x8*)(pA0 + 128 * 64 + i * 2048);
    STAGE_A(0, sAn, ktn); STAGE_A(1, sAn, ktn);
    BAR(); WLG0();
    MM16(4);
    BAR();

    // ---- PH3: rows0-127 x kk1 ; stage next A (hi) ----
#pragma unroll
    for (int i = 0; i < 4; i++) af[i] = *(const bf16x8*)(pA1 + i * 2048);
#pragma unroll
    for (int j = 0; j < 4; j++)
      bf[j] = *(const bf16x8*)(sBc + ((size_t)((4 + quad) * 256) + wn + j * 16 + l16) * 8);
    STAGE_A(2, sAn, ktn); STAGE_A(3, sAn, ktn);
    BAR(); WLG0();
    MM16(0);
    WVM4();  // B ints/scale/zero landed; 4 A-stages may stay in flight
    BAR();

    // ---- PH4: rows128-255 x kk1 ; expand next B -> sBn ----
#pragma unroll
    for (int i = 0; i < 4; i++) af[i] = *(const bf16x8*)(pA1 + 128 * 64 + i * 2048);
    EXPB(sBn);
    BAR(); WLG0();   // drains ds_writes too -> visible before closing BAR
    MM16(4);
    WVM0();  // A stages landed (issued PH2/PH3, >=2 phases earlier)
    BAR();
  }

#undef STAGE_A
#undef LOADB
#undef EXPB
#undef MM16

  // Epilogue. C/D frag layout: col = l16, row = quad*4 + r.
  // gm = m0 + (a>>2)*128 + (a&3)*32 + wm16 + quad*4 + r.
#pragma unroll
  for (int a = 0; a < 8; a++) {
    const int gmb = m0 + (a >> 2) * 128 + (a & 3) * 32 + wm16 + quad * 4;
#pragma unroll
    for (int r = 0; r < 4; r++) {
      const int gm = gmb + r;
      if (MODE == 2) {
        float* crow = (float*)Cv + (size_t)gm * ldc + bn0 + wn;
#pragma unroll
        for (int j = 0; j < 4; j++) crow[j * 16 + l16] = acc[a][j][r];
      } else {
        ushort* crow = (ushort*)Cv + (size_t)gm * ldc + bn0 + wn;
#pragma unroll
        for (int j = 0; j < 4; j++) {
          float v = acc[a][j][r];
          const int cn = j * 16 + l16;
          if (MODE == 1) {
            const float gv = bf2f(crow[cn]);             // gate (bf16)
            v = (gv / (1.0f + __expf(-gv))) * v;         // silu(gate) * up
          }
          crow[cn] = f2bf_rne(v);
        }
      }
    }
  }
}

extern "C" void kernel_launch(void* const* d_in, const int* in_sizes, int n_in,
                              void* d_out, int out_size, void* d_ws, size_t ws_size,
                              hipStream_t stream) {
  (void)n_in; (void)out_size;
  const float*   x   = (const float*)d_in[0];    // fp32 [4096, 4096]
  const int32_t* gq  = (const int32_t*)d_in[1];  // [512, 11008]
  const float*   gs  = (const float*)d_in[2];    // fp32 [32, 11008]
  const int32_t* gz  = (const int32_t*)d_in[3];  // [32, 1376]
  const int32_t* uq  = (const int32_t*)d_in[4];
  const float*   us  = (const float*)d_in[5];
  const int32_t* uz  = (const int32_t*)d_in[6];
  const int32_t* dq  = (const int32_t*)d_in[7];  // [1376, 4096]
  const float*   dsc = (const float*)d_in[8];    // fp32 [86, 4096]
  const int32_t* dz  = (const int32_t*)d_in[9];  // [86, 512]
  float* outp = (float*)d_out;                   // fp32 [4096, 4096]

  const int M = in_sizes[0] / HIDDEN;            // 4096

  // ---- ws plan: xb [M,HIDDEN] bf16 + gi [MC,INTER] bf16 (no wb needed) ----
  const size_t W = ws_size;
  const size_t xb_bytes = (size_t)M * HIDDEN * 2;   // 33.5 MB
  int MC = 256;
  for (int cand = M; cand >= 256; cand >>= 1) {
    if (xb_bytes + (size_t)cand * INTER * 2 <= W) { MC = cand; break; }
  }
  ushort* xb = (ushort*)d_ws;                              // [M, HIDDEN] bf16
  ushort* gi = xb + (size_t)M * HIDDEN;                    // [MC, INTER] bf16

  // Convert x (fp32) -> xb (bf16) once.
  const int n4 = M * HIDDEN / 4;
  f32_to_bf16_kernel<<<(n4 + 255) / 256, 256, 0, stream>>>(x, xb, n4);

  for (int m0 = 0; m0 < M; m0 += MC) {
    const ushort* xm = xb + (size_t)m0 * HIDDEN;
    // Phase 1: gate = x @ Wg   (into gi, bf16)
    gemm_fused_kernel<0><<<dim3(INTER / BN, MC / BM), 512, 0, stream>>>(
        xm, gq, gs, gz, gi, HIDDEN, INTER, HIDDEN, INTER);
    // Phase 2: inter = silu(gate) * (x @ Wu)   (in place over gi)
    gemm_fused_kernel<1><<<dim3(INTER / BN, MC / BM), 512, 0, stream>>>(
        xm, uq, us, uz, gi, HIDDEN, INTER, HIDDEN, INTER);
    // Phase 3: out = inter @ Wd   (fp32 out)
    gemm_fused_kernel<2><<<dim3(HIDDEN / BN, MC / BM), 512, 0, stream>>>(
        gi, dq, dsc, dz, (void*)(outp + (size_t)m0 * HIDDEN), INTER, HIDDEN, INTER, HIDDEN);
  }
}

// Round 5
// 1371.976 us; speedup vs baseline: 1.0690x; 1.0690x over previous
//
#include <hip/hip_runtime.h>
#include <stdint.h>

// FusedGPTQMLP on MI355X (gfx950).
// Round 11: R7 structure (best measured: 256x256 tile, 8 waves, 4 phases,
// counted vmcnt(4) waits, separate dequant kernel) with the MFMA switched
// from 16x16x32 to 32x32x16 (2382 vs 2075 TF ubench => ~15% less MFMA-pipe
// time, half the MFMA instruction count). LDS layouts/staging unchanged.
// ws: xb [M,HIDDEN] bf16 | gi [MC,INTER] bf16 | wb weight chunk (adaptive).

#define HIDDEN 4096
#define INTER  11008
#define BM 256
#define BN 256
#define BK 64

typedef __bf16 bf16x8 __attribute__((ext_vector_type(8)));
typedef float f32x16 __attribute__((ext_vector_type(16)));

__device__ __forceinline__ ushort f2bf_rne(float f) {
  uint32_t u = __float_as_uint(f);
  u += 0x7FFFu + ((u >> 16) & 1u);
  return (ushort)(u >> 16);
}

__device__ __forceinline__ float bf2f(ushort h) {
  return __uint_as_float(((uint32_t)h) << 16);
}

// fp32 -> bf16 bulk convert, 4 elements/thread.
__global__ void f32_to_bf16_kernel(const float* __restrict__ src,
                                   ushort* __restrict__ dst, int n4) {
  const int i = blockIdx.x * 256 + threadIdx.x;
  if (i < n4) {
    const float4 v = ((const float4*)src)[i];
    ushort4 o;
    o.x = f2bf_rne(v.x); o.y = f2bf_rne(v.y);
    o.z = f2bf_rne(v.z); o.w = f2bf_rne(v.w);
    ((ushort4*)dst)[i] = o;
  }
}

// Dequant qweight[k8][n] (8 k-nibbles per int32) into packet layout:
// Bp[(k8*nc + n_local)*8 + j] = W[k8*8+j][n0+n_local], bf16. Scales fp32.
__global__ void dequant_kernel(const int32_t* __restrict__ qw,
                               const float* __restrict__ sc,
                               const int32_t* __restrict__ zr,
                               ushort* __restrict__ Bp,
                               int Nfull, int n0, int nc) {
  const int n_local = blockIdx.x * 128 + threadIdx.x;
  const int k8 = blockIdx.y;
  const int n = n0 + n_local;
  const int g = k8 >> 4;  // groupsize 128 => 16 k8-rows per group
  const uint32_t q = (uint32_t)qw[(size_t)k8 * Nfull + n];
  const float s = sc[(size_t)g * Nfull + n];
  const uint32_t zv = (uint32_t)zr[(size_t)g * (Nfull >> 3) + (n >> 3)];
  const int z1 = (int)((zv >> ((n & 7) * 4)) & 15u) + 1;
  union { ushort h[8]; uint4 v; } o;
#pragma unroll
  for (int j = 0; j < 8; j++) {
    const int qi = (int)((q >> (4 * j)) & 15u) - z1;  // (q - (z+1)), exact int
    o.h[j] = f2bf_rne((float)qi * s);
  }
  *(uint4*)(Bp + ((size_t)k8 * nc + n_local) * 8) = o.v;
}

#define GL_LDS(gp, lp)                                                        \
  __builtin_amdgcn_global_load_lds(                                           \
      (const __attribute__((address_space(1))) uint32_t*)(gp),                \
      (__attribute__((address_space(3))) uint32_t*)(lp), 16, 0, 0)
#define BAR()  do { __builtin_amdgcn_s_barrier(); asm volatile("" ::: "memory"); } while (0)
#define WVM4() asm volatile("s_waitcnt vmcnt(4)" ::: "memory")
#define WVM0() asm volatile("s_waitcnt vmcnt(0)" ::: "memory")
#define WLG0() asm volatile("s_waitcnt lgkmcnt(0)" ::: "memory")

// C[m, n] = A[m, :] @ W[:, n] over this chunk's nc columns.
// A: bf16 [rows, lda] (pre-offset). Bp: packets [K/8][nc][8] bf16.
// MODE 0: C bf16. MODE 1: C bf16 = silu(C_old) * result. MODE 2: C fp32.
//
// 32x32x16 MFMA. Wave (wm in {0,1}) x (wn in {0..3}); wave tile 128x64:
// row blocks rb=0..3 at global rows rb*64 + wm*32 (so rb0,1 live in A-slab
// rows 0-127, rb2,3 in rows 128-255 for BOTH wm -- matches slab staging).
// Lane: l32 = lane&31 (row/col), hl = lane>>5 (k-octet within K=16).
// A fragment (rb, ks): octet p = 2*ks + hl at row rb*64+wm*32+l32, LDS slot
// p ^ (l32&7) (XOR swizzle). B fragment (cb, ks): packet p, col
// wn*64+cb*32+l32. Phases as R7: kk-half x row-half, reads 8/4/8/4,
// stages A0/B0/A1/B1, counted vmcnt(4) at 3 boundaries.
template <int MODE>
__launch_bounds__(512, 2)
__global__ void gemm_bt_kernel(const ushort* __restrict__ A,
                               const ushort* __restrict__ Bp,
                               void* __restrict__ Cv,
                               int K, int nc, int lda, int ldc) {
  __shared__ ushort sAs[2][BM * BK];            // 2 x 32 KB
  __shared__ ushort sBs[2][(BK / 8) * BN * 8];  // 2 x 32 KB

  const int tid = threadIdx.x;
  const int w = tid >> 6;
  const int lane = tid & 63;
  const int l32 = lane & 31;
  const int hl = lane >> 5;
  const int wm = w >> 2;            // 0..1 (M)
  const int wn = w & 3;             // 0..3 (N)
  const int sw = l32 & 7;           // A XOR swizzle key (row & 7)

  // Bijective XCD-aware block swizzle (m204 form).
  const int gx = gridDim.x;
  const int nwg = gx * (int)gridDim.y;
  const int orig = blockIdx.y * gx + blockIdx.x;
  const int q8 = nwg >> 3, r8 = nwg & 7;
  const int xcd = orig & 7, sidx = orig >> 3;
  const int wg = (xcd < r8 ? xcd * (q8 + 1) : r8 * (q8 + 1) + (xcd - r8) * q8) + sidx;
  const int m0 = (wg / gx) * BM;
  const int bn0 = (wg % gx) * BN;

  // Staging lane geometry (per-lane global src pre-swizzled; LDS dest linear).
  const int arow = tid >> 3;                      // 0..63 within 64-row slab
  const int apk8 = ((tid & 7) ^ (arow & 7)) * 8;  // swizzled source packet
  const int bpr = tid >> 8;                       // 0..1 packet-row in slab
  const int bcol = tid & 255;
  const ushort* aSrc = A + (size_t)(m0 + arow) * lda + apk8;
  const ushort* bSrc = Bp + ((size_t)bpr * nc + bn0 + bcol) * 8;

  f32x16 acc[4][2];  // [rb][cb]
#pragma unroll
  for (int rb = 0; rb < 4; rb++)
#pragma unroll
    for (int cb = 0; cb < 2; cb++)
#pragma unroll
      for (int e = 0; e < 16; e++) acc[rb][cb][e] = 0.0f;

  const int NT = K / BK;

#define STAGE_A(r, buf, kt) \
  GL_LDS(aSrc + (size_t)(r) * 64 * lda + (kt), (buf) + (r) * 4096 + w * 512)
#define STAGE_B(r, buf, kp) \
  GL_LDS(bSrc + ((kp) + (size_t)(r) * 2) * (size_t)nc * 8, (buf) + (r) * 4096 + w * 512)

  // Read A fragments for row-half rh (rb = rh*2, rh*2+1) and kk-half kkh.
  // af[rbi][ksh]; octet p = kkh*4 + ksh*2 + hl; slot = p ^ sw.
#define RD_A(sAc, rh, kkh)                                                     \
  do {                                                                         \
    _Pragma("unroll") for (int rbi = 0; rbi < 2; rbi++) {                      \
      const ushort* _a =                                                       \
          (sAc) + (size_t)(((rh) * 2 + rbi) * 64 + wm * 32 + l32) * 64;        \
      _Pragma("unroll") for (int ksh = 0; ksh < 2; ksh++)                      \
        af[rbi][ksh] = *(const bf16x8*)(                                       \
            _a + ((((kkh) * 4 + ksh * 2 + hl) ^ sw) * 8));                     \
    }                                                                          \
  } while (0)
  // Read B fragments for kk-half kkh: bfr[cb][ksh] at packet p, col.
#define RD_B(sBc, kkh)                                                         \
  do {                                                                         \
    _Pragma("unroll") for (int cb = 0; cb < 2; cb++) {                         \
      const int _c = wn * 64 + cb * 32 + l32;                                  \
      _Pragma("unroll") for (int ksh = 0; ksh < 2; ksh++)                      \
        bfr[cb][ksh] = *(const bf16x8*)(                                       \
            (sBc) + ((size_t)(((kkh) * 4 + ksh * 2 + hl) * 256) + _c) * 8);    \
    }                                                                          \
  } while (0)
  // 8 MFMA: row-half rh x cb x ksh into acc[rh*2+rbi][cb].
#define MM8(rh)                                                                \
  do {                                                                         \
    __builtin_amdgcn_s_setprio(1);                                             \
    _Pragma("unroll") for (int ksh = 0; ksh < 2; ksh++)                        \
    _Pragma("unroll") for (int rbi = 0; rbi < 2; rbi++)                        \
    _Pragma("unroll") for (int cb = 0; cb < 2; cb++)                           \
      acc[(rh) * 2 + rbi][cb] = __builtin_amdgcn_mfma_f32_32x32x16_bf16(       \
          af[rbi][ksh], bfr[cb][ksh], acc[(rh) * 2 + rbi][cb], 0, 0, 0);       \
    __builtin_amdgcn_s_setprio(0);                                             \
  } while (0)

  // Prologue: stage tile 0 in order A-lo, B-lo, A-hi, B-hi.
  {
    ushort* sA0 = sAs[0];
    ushort* sB0 = sBs[0];
    STAGE_A(0, sA0, (size_t)0); STAGE_A(1, sA0, (size_t)0);  // rows 0-127
    STAGE_B(0, sB0, (size_t)0); STAGE_B(1, sB0, (size_t)0);  // packets 0-3
    STAGE_A(2, sA0, (size_t)0); STAGE_A(3, sA0, (size_t)0);  // rows 128-255
    STAGE_B(2, sB0, (size_t)0); STAGE_B(3, sB0, (size_t)0);  // packets 4-7
  }

#pragma unroll 1
  for (int t = 0; t < NT; ++t) {
    const ushort* sAc = sAs[t & 1];
    const ushort* sBc = sBs[t & 1];
    ushort* sAn = sAs[(t & 1) ^ 1];
    ushort* sBn = sBs[(t & 1) ^ 1];
    const int tn = (t + 1 < NT) ? t + 1 : t;  // clamp: re-stage last tile
    const size_t ktn = (size_t)tn * BK;
    const size_t kpn = (size_t)tn * 8;

    bf16x8 af[2][2], bfr[2][2];

    // Boundary: A-lo,B-lo of this tile landed; A-hi,B-hi may be in flight.
    WVM4(); BAR();

    // ---- PH1: rows lo x kk0 ; stage next A-lo ----
    RD_A(sAc, 0, 0); RD_B(sBc, 0);
    STAGE_A(0, sAn, ktn); STAGE_A(1, sAn, ktn);
    BAR(); WLG0();
    MM8(0);
    WVM4();  // this tile's A-hi landed
    BAR();

    // ---- PH2: rows hi x kk0 (bfr reused) ; stage next B-lo ----
    RD_A(sAc, 1, 0);
    STAGE_B(0, sBn, kpn); STAGE_B(1, sBn, kpn);
    BAR(); WLG0();
    MM8(1);
    WVM4();  // this tile's B-hi landed
    BAR();

    // ---- PH3: rows lo x kk1 ; stage next A-hi ----
    RD_A(sAc, 0, 1); RD_B(sBc, 1);
    STAGE_A(2, sAn, ktn); STAGE_A(3, sAn, ktn);
    BAR(); WLG0();
    MM8(0);
    BAR();  // no vmcnt here

    // ---- PH4: rows hi x kk1 ; stage next B-hi ----
    RD_A(sAc, 1, 1);
    STAGE_B(2, sBn, kpn); STAGE_B(3, sBn, kpn);
    BAR(); WLG0();
    MM8(1);
    // closing vmcnt+barrier folded into next iteration's loop top
  }
  WVM0();  // drain trailing (re-)staged loads before epilogue

#undef STAGE_A
#undef STAGE_B
#undef RD_A
#undef RD_B
#undef MM8

  // Epilogue. 32x32 C/D layout (m74/m101 verified):
  // col = lane&31, row = (reg&3) + 8*(reg>>2) + 4*(lane>>5).
  // gm = m0 + rb*64 + wm*32 + row; gn = bn0 + wn*64 + cb*32 + l32.
#pragma unroll
  for (int rb = 0; rb < 4; rb++) {
#pragma unroll
    for (int r = 0; r < 16; r++) {
      const int gm = m0 + rb * 64 + wm * 32 + (r & 3) + 8 * (r >> 2) + 4 * hl;
      if (MODE == 2) {
        float* crow = (float*)Cv + (size_t)gm * ldc + bn0 + wn * 64;
#pragma unroll
        for (int cb = 0; cb < 2; cb++) crow[cb * 32 + l32] = acc[rb][cb][r];
      } else {
        ushort* crow = (ushort*)Cv + (size_t)gm * ldc + bn0 + wn * 64;
#pragma unroll
        for (int cb = 0; cb < 2; cb++) {
          float v = acc[rb][cb][r];
          const int cn = cb * 32 + l32;
          if (MODE == 1) {
            const float gv = bf2f(crow[cn]);             // gate (bf16)
            v = (gv / (1.0f + __expf(-gv))) * v;         // silu(gate) * up
          }
          crow[cn] = f2bf_rne(v);
        }
      }
    }
  }
}

extern "C" void kernel_launch(void* const* d_in, const int* in_sizes, int n_in,
                              void* d_out, int out_size, void* d_ws, size_t ws_size,
                              hipStream_t stream) {
  (void)n_in; (void)out_size;
  const float*   x   = (const float*)d_in[0];    // fp32 [4096, 4096]
  const int32_t* gq  = (const int32_t*)d_in[1];  // [512, 11008]
  const float*   gs  = (const float*)d_in[2];    // fp32 [32, 11008]
  const int32_t* gz  = (const int32_t*)d_in[3];  // [32, 1376]
  const int32_t* uq  = (const int32_t*)d_in[4];
  const float*   us  = (const float*)d_in[5];
  const int32_t* uz  = (const int32_t*)d_in[6];
  const int32_t* dq  = (const int32_t*)d_in[7];  // [1376, 4096]
  const float*   dsc = (const float*)d_in[8];    // fp32 [86, 4096]
  const int32_t* dz  = (const int32_t*)d_in[9];  // [86, 512]
  float* outp = (float*)d_out;                   // fp32 [4096, 4096]

  const int M = in_sizes[0] / HIDDEN;            // 4096

  // ---- ws-size-adaptive plan (all scratch strictly inside d_ws) ----
  const size_t W = ws_size;
  const size_t col12 = (size_t)HIDDEN * 2;   // 8192 B per dequant col (K=HIDDEN)
  const size_t col3  = (size_t)INTER * 2;    // 22016 B per dequant col (K=INTER)
  const size_t xb_bytes = (size_t)M * HIDDEN * 2;   // 33.5 MB
  int MC = 256;
  for (int cand = M; cand >= 256; cand >>= 1) {
    if (xb_bytes + (size_t)cand * INTER * 2 + col3 * 256 <= W) { MC = cand; break; }
  }
  ushort* xb = (ushort*)d_ws;                              // [M, HIDDEN] bf16
  ushort* gi = xb + (size_t)M * HIDDEN;                    // [MC, INTER] bf16
  ushort* wb = gi + (size_t)MC * INTER;                    // weight chunk
  const size_t used = xb_bytes + (size_t)MC * INTER * 2;
  const size_t wbuf = (W > used) ? W - used : 0;
  int NC12 = (int)(wbuf / col12); NC12 &= ~255;
  if (NC12 < 256) NC12 = 256;
  if (NC12 > INTER) NC12 = INTER;            // 11008 = 43*256
  int NC3 = (int)(wbuf / col3); NC3 &= ~255;
  if (NC3 < 256) NC3 = 256;
  if (NC3 > HIDDEN) NC3 = HIDDEN;

  // Convert x (fp32) -> xb (bf16) once.
  const int n4 = M * HIDDEN / 4;
  f32_to_bf16_kernel<<<(n4 + 255) / 256, 256, 0, stream>>>(x, xb, n4);

  for (int m0 = 0; m0 < M; m0 += MC) {
    const ushort* xm = xb + (size_t)m0 * HIDDEN;
    // Phase 1: gate = x @ Wg   (into gi, bf16)
    for (int n0 = 0; n0 < INTER; ) {
      int nc = INTER - n0; if (nc > NC12) nc = NC12;
      dequant_kernel<<<dim3(nc / 128, HIDDEN / 8), 128, 0, stream>>>(
          gq, gs, gz, wb, INTER, n0, nc);
      gemm_bt_kernel<0><<<dim3(nc / BN, MC / BM), 512, 0, stream>>>(
          xm, wb, gi + n0, HIDDEN, nc, HIDDEN, INTER);
      n0 += nc;
    }
    // Phase 2: inter = silu(gate) * (x @ Wu)   (in place over gi)
    for (int n0 = 0; n0 < INTER; ) {
      int nc = INTER - n0; if (nc > NC12) nc = NC12;
      dequant_kernel<<<dim3(nc / 128, HIDDEN / 8), 128, 0, stream>>>(
          uq, us, uz, wb, INTER, n0, nc);
      gemm_bt_kernel<1><<<dim3(nc / BN, MC / BM), 512, 0, stream>>>(
          xm, wb, gi + n0, HIDDEN, nc, HIDDEN, INTER);
      n0 += nc;
    }
    // Phase 3: out = inter @ Wd   (fp32 out)
    for (int n0 = 0; n0 < HIDDEN; ) {
      int nc = HIDDEN - n0; if (nc > NC3) nc = NC3;
      dequant_kernel<<<dim3(nc / 128, INTER / 8), 128, 0, stream>>>(
          dq, dsc, dz, wb, HIDDEN, n0, nc);
      gemm_bt_kernel<2><<<dim3(nc / BN, MC / BM), 512, 0, stream>>>(
          gi, wb, (void*)(outp + (size_t)m0 * HIDDEN + n0), INTER, nc, INTER, HIDDEN);
      n0 += nc;
    }
  }
}

// Round 6
// 1188.849 us; speedup vs baseline: 1.2337x; 1.1540x over previous
//
#include <hip/hip_runtime.h>
#include <stdint.h>

// FusedGPTQMLP on MI355X (gfx950).
// Round 12: R7 structure (best measured: 256x256, 8 waves, 16x16x32 MFMA,
// counted vmcnt(4), 0 bank conflicts) with intra-step barriers REMOVED.
// Only ONE barrier per K-step (at the boundary, which alone guards the
// buffer-overwrite hazard: stages into X at step t are issued after the
// barrier, and X's last reads were in step t-1). Blanket lgkmcnt(0) drains
// also removed -- compiler emits fine-grained per-fragment waits. Waves
// free-run within a step => cross-wave MFMA/LDS overlap (2 waves/SIMD).
// ws: xb [M,HIDDEN] bf16 | gi [MC,INTER] bf16 | wb weight chunk (adaptive).

#define HIDDEN 4096
#define INTER  11008
#define BM 256
#define BN 256
#define BK 64

typedef __bf16 bf16x8 __attribute__((ext_vector_type(8)));
typedef float f32x4 __attribute__((ext_vector_type(4)));

__device__ __forceinline__ ushort f2bf_rne(float f) {
  uint32_t u = __float_as_uint(f);
  u += 0x7FFFu + ((u >> 16) & 1u);
  return (ushort)(u >> 16);
}

__device__ __forceinline__ float bf2f(ushort h) {
  return __uint_as_float(((uint32_t)h) << 16);
}

// fp32 -> bf16 bulk convert, 4 elements/thread.
__global__ void f32_to_bf16_kernel(const float* __restrict__ src,
                                   ushort* __restrict__ dst, int n4) {
  const int i = blockIdx.x * 256 + threadIdx.x;
  if (i < n4) {
    const float4 v = ((const float4*)src)[i];
    ushort4 o;
    o.x = f2bf_rne(v.x); o.y = f2bf_rne(v.y);
    o.z = f2bf_rne(v.z); o.w = f2bf_rne(v.w);
    ((ushort4*)dst)[i] = o;
  }
}

// Dequant qweight[k8][n] (8 k-nibbles per int32) into packet layout:
// Bp[(k8*nc + n_local)*8 + j] = W[k8*8+j][n0+n_local], bf16. Scales fp32.
__global__ void dequant_kernel(const int32_t* __restrict__ qw,
                               const float* __restrict__ sc,
                               const int32_t* __restrict__ zr,
                               ushort* __restrict__ Bp,
                               int Nfull, int n0, int nc) {
  const int n_local = blockIdx.x * 128 + threadIdx.x;
  const int k8 = blockIdx.y;
  const int n = n0 + n_local;
  const int g = k8 >> 4;  // groupsize 128 => 16 k8-rows per group
  const uint32_t q = (uint32_t)qw[(size_t)k8 * Nfull + n];
  const float s = sc[(size_t)g * Nfull + n];
  const uint32_t zv = (uint32_t)zr[(size_t)g * (Nfull >> 3) + (n >> 3)];
  const int z1 = (int)((zv >> ((n & 7) * 4)) & 15u) + 1;
  union { ushort h[8]; uint4 v; } o;
#pragma unroll
  for (int j = 0; j < 8; j++) {
    const int qi = (int)((q >> (4 * j)) & 15u) - z1;  // (q - (z+1)), exact int
    o.h[j] = f2bf_rne((float)qi * s);
  }
  *(uint4*)(Bp + ((size_t)k8 * nc + n_local) * 8) = o.v;
}

#define GL_LDS(gp, lp)                                                        \
  __builtin_amdgcn_global_load_lds(                                           \
      (const __attribute__((address_space(1))) uint32_t*)(gp),                \
      (__attribute__((address_space(3))) uint32_t*)(lp), 16, 0, 0)
#define BAR()  do { __builtin_amdgcn_s_barrier(); asm volatile("" ::: "memory"); } while (0)
#define WVM4() asm volatile("s_waitcnt vmcnt(4)" ::: "memory")
#define WVM0() asm volatile("s_waitcnt vmcnt(0)" ::: "memory")

// C[m, n] = A[m, :] @ W[:, n] over this chunk's nc columns.
// A: bf16 [rows, lda] (pre-offset). Bp: packets [K/8][nc][8] bf16.
// MODE 0: C bf16 = result. MODE 1: C bf16 = silu(C_old) * result (SwiGLU).
// MODE 2: C fp32 = result (final output).
// 256x256 tile, BK=64, 8 waves (2M x 4N), wave tile 128x64, 4 phase-bodies
// x 16 MFMA per K-step. ONE barrier per step; per-wave counted vmcnt(4)
// ledger (identical to R7, per-wave valid without barriers):
//   boundary: wait A-lo,B-lo of this tile (outstanding<=4: A-hi,B-hi)
//   after PH1 (issued next A-lo): wait this tile's A-hi
//   after PH2 (issued next B-lo): wait this tile's B-hi
//   PH3/PH4 stage next A-hi / B-hi; closing wait folds into next boundary.
template <int MODE>
__launch_bounds__(512, 2)
__global__ void gemm_bt_kernel(const ushort* __restrict__ A,
                               const ushort* __restrict__ Bp,
                               void* __restrict__ Cv,
                               int K, int nc, int lda, int ldc) {
  __shared__ ushort sAs[2][BM * BK];            // 2 x 32 KB
  __shared__ ushort sBs[2][(BK / 8) * BN * 8];  // 2 x 32 KB

  const int tid = threadIdx.x;
  const int w = tid >> 6;
  const int lane = tid & 63;
  const int l16 = lane & 15;
  const int quad = lane >> 4;
  const int wm16 = (w >> 2) * 16;   // 2 waves along M
  const int wn = (w & 3) * 64;      // 4 waves along N
  const int swz = l16 & 7;          // A-tile XOR swizzle key (row & 7)

  // Bijective XCD-aware block swizzle (m204 form).
  const int gx = gridDim.x;
  const int nwg = gx * (int)gridDim.y;
  const int orig = blockIdx.y * gx + blockIdx.x;
  const int q8 = nwg >> 3, r8 = nwg & 7;
  const int xcd = orig & 7, sidx = orig >> 3;
  const int wg = (xcd < r8 ? xcd * (q8 + 1) : r8 * (q8 + 1) + (xcd - r8) * q8) + sidx;
  const int m0 = (wg / gx) * BM;
  const int bn0 = (wg % gx) * BN;

  // Staging lane geometry (per-lane global src pre-swizzled; LDS dest linear).
  const int arow = tid >> 3;                      // 0..63 within 64-row slab
  const int apk8 = ((tid & 7) ^ (arow & 7)) * 8;  // swizzled source packet
  const int bpr = tid >> 8;                       // 0..1 packet-row in slab
  const int bcol = tid & 255;
  const ushort* aSrc = A + (size_t)(m0 + arow) * lda + apk8;
  const ushort* bSrc = Bp + ((size_t)bpr * nc + bn0 + bcol) * 8;

  f32x4 acc[8][4];
#pragma unroll
  for (int a = 0; a < 8; a++)
#pragma unroll
    for (int j = 0; j < 4; j++) acc[a][j] = (f32x4){0.f, 0.f, 0.f, 0.f};

  const int NT = K / BK;

#define STAGE_A(r, buf, kt) \
  GL_LDS(aSrc + (size_t)(r) * 64 * lda + (kt), (buf) + (r) * 4096 + w * 512)
#define STAGE_B(r, buf, kp) \
  GL_LDS(bSrc + ((kp) + (size_t)(r) * 2) * (size_t)nc * 8, (buf) + (r) * 4096 + w * 512)

#define MM16(base)                                                       \
  do {                                                                   \
    __builtin_amdgcn_s_setprio(1);                                       \
    _Pragma("unroll") for (int i = 0; i < 4; i++)                        \
    _Pragma("unroll") for (int j = 0; j < 4; j++)                        \
      acc[(base) + i][j] = __builtin_amdgcn_mfma_f32_16x16x32_bf16(      \
          af[i], bf[j], acc[(base) + i][j], 0, 0, 0);                    \
    __builtin_amdgcn_s_setprio(0);                                       \
  } while (0)

  // Prologue: stage tile 0 in stream order A-lo, B-lo, A-hi, B-hi.
  {
    ushort* sA0 = sAs[0];
    ushort* sB0 = sBs[0];
    STAGE_A(0, sA0, (size_t)0); STAGE_A(1, sA0, (size_t)0);  // rows 0-127
    STAGE_B(0, sB0, (size_t)0); STAGE_B(1, sB0, (size_t)0);  // packets 0-3
    STAGE_A(2, sA0, (size_t)0); STAGE_A(3, sA0, (size_t)0);  // rows 128-255
    STAGE_B(2, sB0, (size_t)0); STAGE_B(3, sB0, (size_t)0);  // packets 4-7
  }

#pragma unroll 1
  for (int t = 0; t < NT; ++t) {
    const ushort* sAc = sAs[t & 1];
    const ushort* sBc = sBs[t & 1];
    ushort* sAn = sAs[(t & 1) ^ 1];
    ushort* sBn = sBs[(t & 1) ^ 1];
    const int tn = (t + 1 < NT) ? t + 1 : t;  // clamp: re-stage last tile
    const size_t ktn = (size_t)tn * BK;
    const size_t kpn = (size_t)tn * 8;

    bf16x8 af[4], bf[4];
    const ushort* pA0 = sAc + (size_t)(wm16 + l16) * 64 + ((quad ^ swz) * 8);
    const ushort* pA1 = sAc + (size_t)(wm16 + l16) * 64 + (((4 ^ quad) ^ swz) * 8);

    // Boundary: A-lo,B-lo of this tile landed; A-hi,B-hi may be in flight.
    // The ONLY barrier per step: after it, all waves have finished reading
    // the buffer this step stages into (its last reads were step t-1).
    WVM4(); BAR();

    // ---- PH1: rows0-127 x kk0 ; stage next A-lo ----
#pragma unroll
    for (int i = 0; i < 4; i++) af[i] = *(const bf16x8*)(pA0 + i * 2048);
#pragma unroll
    for (int j = 0; j < 4; j++)
      bf[j] = *(const bf16x8*)(sBc + ((size_t)(quad * 256) + wn + j * 16 + l16) * 8);
    STAGE_A(0, sAn, ktn); STAGE_A(1, sAn, ktn);
    MM16(0);
    WVM4();  // this tile's A-hi landed

    // ---- PH2: rows128-255 x kk0 (bf reused) ; stage next B-lo ----
#pragma unroll
    for (int i = 0; i < 4; i++) af[i] = *(const bf16x8*)(pA0 + 128 * 64 + i * 2048);
    STAGE_B(0, sBn, kpn); STAGE_B(1, sBn, kpn);
    MM16(4);
    WVM4();  // this tile's B-hi landed

    // ---- PH3: rows0-127 x kk1 ; stage next A-hi ----
#pragma unroll
    for (int i = 0; i < 4; i++) af[i] = *(const bf16x8*)(pA1 + i * 2048);
#pragma unroll
    for (int j = 0; j < 4; j++)
      bf[j] = *(const bf16x8*)(sBc + ((size_t)((4 + quad) * 256) + wn + j * 16 + l16) * 8);
    STAGE_A(2, sAn, ktn); STAGE_A(3, sAn, ktn);
    MM16(0);

    // ---- PH4: rows128-255 x kk1 ; stage next B-hi ----
#pragma unroll
    for (int i = 0; i < 4; i++) af[i] = *(const bf16x8*)(pA1 + 128 * 64 + i * 2048);
    STAGE_B(2, sBn, kpn); STAGE_B(3, sBn, kpn);
    MM16(4);
    // closing vmcnt folds into next iteration's boundary WVM4
  }
  WVM0();  // drain trailing (re-)staged loads before epilogue

#undef STAGE_A
#undef STAGE_B
#undef MM16

  // Epilogue. C/D frag layout: col = l16, row = quad*4 + r.
  // gm = m0 + (a>>2)*128 + (a&3)*32 + wm16 + quad*4 + r.
#pragma unroll
  for (int a = 0; a < 8; a++) {
    const int gmb = m0 + (a >> 2) * 128 + (a & 3) * 32 + wm16 + quad * 4;
#pragma unroll
    for (int r = 0; r < 4; r++) {
      const int gm = gmb + r;
      if (MODE == 2) {
        float* crow = (float*)Cv + (size_t)gm * ldc + bn0 + wn;
#pragma unroll
        for (int j = 0; j < 4; j++) crow[j * 16 + l16] = acc[a][j][r];
      } else {
        ushort* crow = (ushort*)Cv + (size_t)gm * ldc + bn0 + wn;
#pragma unroll
        for (int j = 0; j < 4; j++) {
          float v = acc[a][j][r];
          const int cn = j * 16 + l16;
          if (MODE == 1) {
            const float gv = bf2f(crow[cn]);             // gate (bf16)
            v = (gv / (1.0f + __expf(-gv))) * v;         // silu(gate) * up
          }
          crow[cn] = f2bf_rne(v);
        }
      }
    }
  }
}

extern "C" void kernel_launch(void* const* d_in, const int* in_sizes, int n_in,
                              void* d_out, int out_size, void* d_ws, size_t ws_size,
                              hipStream_t stream) {
  (void)n_in; (void)out_size;
  const float*   x   = (const float*)d_in[0];    // fp32 [4096, 4096]
  const int32_t* gq  = (const int32_t*)d_in[1];  // [512, 11008]
  const float*   gs  = (const float*)d_in[2];    // fp32 [32, 11008]
  const int32_t* gz  = (const int32_t*)d_in[3];  // [32, 1376]
  const int32_t* uq  = (const int32_t*)d_in[4];
  const float*   us  = (const float*)d_in[5];
  const int32_t* uz  = (const int32_t*)d_in[6];
  const int32_t* dq  = (const int32_t*)d_in[7];  // [1376, 4096]
  const float*   dsc = (const float*)d_in[8];    // fp32 [86, 4096]
  const int32_t* dz  = (const int32_t*)d_in[9];  // [86, 512]
  float* outp = (float*)d_out;                   // fp32 [4096, 4096]

  const int M = in_sizes[0] / HIDDEN;            // 4096

  // ---- ws-size-adaptive plan (all scratch strictly inside d_ws) ----
  const size_t W = ws_size;
  const size_t col12 = (size_t)HIDDEN * 2;   // 8192 B per dequant col (K=HIDDEN)
  const size_t col3  = (size_t)INTER * 2;    // 22016 B per dequant col (K=INTER)
  const size_t xb_bytes = (size_t)M * HIDDEN * 2;   // 33.5 MB
  int MC = 256;
  for (int cand = M; cand >= 256; cand >>= 1) {
    if (xb_bytes + (size_t)cand * INTER * 2 + col3 * 256 <= W) { MC = cand; break; }
  }
  ushort* xb = (ushort*)d_ws;                              // [M, HIDDEN] bf16
  ushort* gi = xb + (size_t)M * HIDDEN;                    // [MC, INTER] bf16
  ushort* wb = gi + (size_t)MC * INTER;                    // weight chunk
  const size_t used = xb_bytes + (size_t)MC * INTER * 2;
  const size_t wbuf = (W > used) ? W - used : 0;
  int NC12 = (int)(wbuf / col12); NC12 &= ~255;
  if (NC12 < 256) NC12 = 256;
  if (NC12 > INTER) NC12 = INTER;            // 11008 = 43*256
  int NC3 = (int)(wbuf / col3); NC3 &= ~255;
  if (NC3 < 256) NC3 = 256;
  if (NC3 > HIDDEN) NC3 = HIDDEN;

  // Convert x (fp32) -> xb (bf16) once.
  const int n4 = M * HIDDEN / 4;
  f32_to_bf16_kernel<<<(n4 + 255) / 256, 256, 0, stream>>>(x, xb, n4);

  for (int m0 = 0; m0 < M; m0 += MC) {
    const ushort* xm = xb + (size_t)m0 * HIDDEN;
    // Phase 1: gate = x @ Wg   (into gi, bf16)
    for (int n0 = 0; n0 < INTER; ) {
      int nc = INTER - n0; if (nc > NC12) nc = NC12;
      dequant_kernel<<<dim3(nc / 128, HIDDEN / 8), 128, 0, stream>>>(
          gq, gs, gz, wb, INTER, n0, nc);
      gemm_bt_kernel<0><<<dim3(nc / BN, MC / BM), 512, 0, stream>>>(
          xm, wb, gi + n0, HIDDEN, nc, HIDDEN, INTER);
      n0 += nc;
    }
    // Phase 2: inter = silu(gate) * (x @ Wu)   (in place over gi)
    for (int n0 = 0; n0 < INTER; ) {
      int nc = INTER - n0; if (nc > NC12) nc = NC12;
      dequant_kernel<<<dim3(nc / 128, HIDDEN / 8), 128, 0, stream>>>(
          uq, us, uz, wb, INTER, n0, nc);
      gemm_bt_kernel<1><<<dim3(nc / BN, MC / BM), 512, 0, stream>>>(
          xm, wb, gi + n0, HIDDEN, nc, HIDDEN, INTER);
      n0 += nc;
    }
    // Phase 3: out = inter @ Wd   (fp32 out)
    for (int n0 = 0; n0 < HIDDEN; ) {
      int nc = HIDDEN - n0; if (nc > NC3) nc = NC3;
      dequant_kernel<<<dim3(nc / 128, INTER / 8), 128, 0, stream>>>(
          dq, dsc, dz, wb, HIDDEN, n0, nc);
      gemm_bt_kernel<2><<<dim3(nc / BN, MC / BM), 512, 0, stream>>>(
          gi, wb, (void*)(outp + (size_t)m0 * HIDDEN + n0), INTER, nc, INTER, HIDDEN);
      n0 += nc;
    }
  }
}